// Round 17
// baseline (156.733 us; speedup 1.0000x reference)
//
#include <hip/hip_runtime.h>

#define BB   32
#define NN   512
#define NH   8
#define FIN  768
#define FHID 64
#define NROWS (BB*NN)   // 16384

typedef __attribute__((ext_vector_type(8))) short bf16x8;
typedef __attribute__((ext_vector_type(4))) short s16x4;
typedef __attribute__((ext_vector_type(4))) float f32x4;
typedef unsigned long long u64;
typedef unsigned short u16;
typedef long i64;

__device__ __forceinline__ float lrelu_f(float s){ return fmaxf(s, 0.2f*s); }
__device__ __forceinline__ float elu_f(float s){ return s > 0.f ? s : expm1f(s); }
__device__ __forceinline__ short f2bf(float f){
  unsigned u = __float_as_uint(f);
  return (short)((u + 0x7fffu + ((u >> 16) & 1u)) >> 16);   // RNE
}
__device__ __forceinline__ float bf2f(short s){
  return __uint_as_float(((unsigned)(u16)s) << 16);
}
// packed {bf16(lo), bf16(hi)} in one u32 — single VOP3 (RNE)
__device__ __forceinline__ unsigned cvt_pk_bf16(float lo, float hi){
  unsigned r;
  asm("v_cvt_pk_bf16_f32 %0, %1, %2" : "=v"(r) : "v"(lo), "v"(hi));
  return r;
}
// raw HW 2^x (1 instruction; very negative input -> 0)
__device__ __forceinline__ float exp2_fast(float x){
  float r;
  asm("v_exp_f32 %0, %1" : "=v"(r) : "v"(x));
  return r;
}
// packed {fp8(lo), fp8(hi)} in low 16 bits (OCP e4m3)
__device__ __forceinline__ unsigned cvt_pk_fp8(float lo, float hi){
  return (unsigned)__builtin_amdgcn_cvt_pk_fp8_f32(lo, hi, 0, false);
}
// async global->LDS DMA, 16B per lane (wave-uniform LDS base + lane*16)
__device__ __forceinline__ void gll16(const void* g, void* l){
  __builtin_amdgcn_global_load_lds(
      (const __attribute__((address_space(1))) void*)g,
      (__attribute__((address_space(3))) void*)l, 16, 0, 0);
}

// ---------------------------------------------------------------------------
// K1a: adjacency -> bitmask words
// ---------------------------------------------------------------------------
__global__ __launch_bounds__(256) void prep_kernel(
    const int* __restrict__ adj,
    u64* __restrict__ maskw)
{
  int row  = blockIdx.x * 4 + (threadIdx.x >> 6);
  int lane = threadIdx.x & 63;
  const int* arow = adj + (long)row * NN;
  #pragma unroll
  for (int w = 0; w < 8; ++w) {
    u64 bal = __ballot(arow[w*64 + lane] > 0);
    if (lane == 0) maskw[(long)row*8 + w] = bal;
  }
}

// ---------------------------------------------------------------------------
// K1b: per-type gathered row lists; 3 global atomics per block.
// ---------------------------------------------------------------------------
__global__ __launch_bounds__(256) void rowlist_kernel(
    const float* __restrict__ vt,
    int* __restrict__ rowlist, int* __restrict__ counts)
{
  __shared__ int lc[3];
  __shared__ int lbase[3];
  int tid = threadIdx.x;
  int row = blockIdx.x * 256 + tid;
  if (tid < 3) lc[tid] = 0;
  __syncthreads();
  const float* v = vt + (long)row*3;
  int t = v[1] > 0.5f ? 1 : (v[2] > 0.5f ? 2 : 0);
  int p = atomicAdd(&lc[t], 1);
  __syncthreads();
  if (tid < 3) lbase[tid] = atomicAdd(&counts[tid], lc[tid]);
  __syncthreads();
  rowlist[t*NROWS + lbase[t] + p] = row;
}

// ---------------------------------------------------------------------------
// K2: weight cast. Round-17: w1 written DIRECTLY in gemm1's DMA-chunk order
// w1tt[(t*4+hb)][kiter][kg][col 0..127][8] (two contiguous 16B stores per
// thread per k0) — retile_w1 kernel deleted. w2 -> w2t unchanged.
// ---------------------------------------------------------------------------
__global__ __launch_bounds__(256) void conv_w(
    const float* __restrict__ w1, const float* __restrict__ w2,
    u16* __restrict__ w1tt, u16* __restrict__ w2t)
{
  __shared__ float tile[64][68];
  int bid = blockIdx.x, tid = threadIdx.x;
  const float* src; int K;
  if (bid < 24) { src = w1 + (long)bid*768*64; K = 768; }
  else { src = w2 + (long)(bid - 24)*512*64; K = 512; }
  int kq = blockIdx.y;
  int kstart = kq * (K >> 2), kend = kstart + (K >> 2);

  for (int k0 = kstart; k0 < kend; k0 += 64) {
    __syncthreads();
    #pragma unroll
    for (int i = 0; i < 4; ++i) {
      int kk = i*16 + (tid >> 4);
      int oo = (tid & 15) * 4;
      float4 v = *(const float4*)(src + (long)(k0 + kk)*64 + oo);
      *(float4*)&tile[kk][oo] = v;
    }
    __syncthreads();
    int o = tid >> 2, kp = (tid & 3) * 16;
    unsigned pk[8];
    #pragma unroll
    for (int j = 0; j < 8; ++j)
      pk[j] = cvt_pk_bf16(tile[kp + 2*j][o], tile[kp + 2*j + 1][o]);
    if (bid < 24) {
      int t = bid >> 3, head = bid & 7;
      int hb = head >> 1, col = (head & 1)*64 + o;
      int k = k0 + kp;                       // multiple of 16
      int kiter = k >> 5, kg = (k >> 3) & 3; // kg in {0,2}
      u16* base = w1tt + (((long)(t*4 + hb)*24 + kiter)*4096) + kg*1024 + col*8;
      *(bf16x8*)base          = *(bf16x8*)&pk[0];   // k .. k+7
      *(bf16x8*)(base + 1024) = *(bf16x8*)&pk[4];   // k+8 .. k+15
    } else {
      int t = bid - 24;
      u16* d = w2t + ((long)t*64 + o)*512 + k0 + kp;
      #pragma unroll
      for (int j = 0; j < 8; ++j) *(unsigned*)(d + 2*j) = pk[j];
    }
    __syncthreads();
  }
}

// ---------------------------------------------------------------------------
// K3: layer-1 gathered GEMM, bf16 MFMA. Round-17: BM=128 x BN=128, 4 waves
// (wave tile 64x64, acc[4][4], 16 MFMA/iter) — per-barrier compute doubled
// so the per-iteration DMA-drain latency (the __syncthreads vmcnt(0) drain,
// unavoidable at HIP level) is amortized over 2x the math; block count
// 1056 -> 516. B staged via global_load_lds DMA from w1tt chunks.
// ---------------------------------------------------------------------------
__global__ __launch_bounds__(256) void gemm1_mfma(
    const float* __restrict__ emb,
    const u16* __restrict__ w1tt,
    const int* __restrict__ rowlist, const int* __restrict__ counts,
    u16* __restrict__ hp1b)
{
  int i   = blockIdx.x;           // 0..515
  int t   = i / 172;
  int r   = i - t*172;
  int cnt = counts[t];
  int hb  = r & 3;
  int rb  = r >> 2;               // 0..42
  int r0  = rb * 128;
  if (r0 >= cnt) return;

  __shared__ short aT[2][4*130*8];     // [kg][130 rows pad][8]  2x8.3KB
  __shared__ short bT[2][4096];        // [kg][128 col][8] linear (DMA dest)
  __shared__ int rowsS[128];

  int tid = threadIdx.x;
  if (tid < 128) {
    int rr = r0 + tid;
    rowsS[tid] = (rr < cnt) ? rowlist[t*NROWS + rr] : -1;
  }
  __syncthreads();

  int ar = tid >> 1, ac = tid & 1;     // row 0..127, k-half 0..1
  int sg = rowsS[ar]; if (sg < 0) sg = rowsS[0];
  const float* aP = emb + (long)sg*768 + ac*16;

  const u16* bBase = w1tt + ((long)(t*4 + hb)*24)*4096;

  int wv = tid >> 6, l = tid & 63;
  int wr = wv >> 1, wc = wv & 1;
  int l15 = l & 15, lg = l >> 4;

  int aw0 = ((ac*2    )*130 + ar)*8;
  int aw1 = ((ac*2 + 1)*130 + ar)*8;

  f32x4 acc[4][4];
  #pragma unroll
  for (int fr = 0; fr < 4; ++fr)
    #pragma unroll
    for (int cf = 0; cf < 4; ++cf) acc[fr][cf] = (f32x4){0.f,0.f,0.f,0.f};

  // prologue: DMA B tile0; stage A tile0; prefetch A tile1 regs
  gll16(bBase + tid*8,        &bT[0][tid*8]);
  gll16(bBase + (256+tid)*8,  &bT[0][(256+tid)*8]);
  float4 rA0 = *(const float4*)(aP);
  float4 rA1 = *(const float4*)(aP + 4);
  float4 rA2 = *(const float4*)(aP + 8);
  float4 rA3 = *(const float4*)(aP + 12);
  {
    unsigned p0 = cvt_pk_bf16(rA0.x, rA0.y), p1 = cvt_pk_bf16(rA0.z, rA0.w);
    unsigned p2 = cvt_pk_bf16(rA1.x, rA1.y), p3 = cvt_pk_bf16(rA1.z, rA1.w);
    unsigned p4 = cvt_pk_bf16(rA2.x, rA2.y), p5 = cvt_pk_bf16(rA2.z, rA2.w);
    unsigned p6 = cvt_pk_bf16(rA3.x, rA3.y), p7 = cvt_pk_bf16(rA3.z, rA3.w);
    *(uint4*)&aT[0][aw0] = make_uint4(p0, p1, p2, p3);
    *(uint4*)&aT[0][aw1] = make_uint4(p4, p5, p6, p7);
  }
  rA0 = *(const float4*)(aP + 32);
  rA1 = *(const float4*)(aP + 36);
  rA2 = *(const float4*)(aP + 40);
  rA3 = *(const float4*)(aP + 44);
  __syncthreads();   // drains DMA + publishes aT[0]

  int cur = 0;
  for (int kiter = 0; kiter < 24; ++kiter) {
    if (kiter < 23) {          // DMA B tile kiter+1 into free buffer
      const u16* bsrc = bBase + (long)(kiter+1)*4096;
      gll16(bsrc + tid*8,       &bT[cur^1][tid*8]);
      gll16(bsrc + (256+tid)*8, &bT[cur^1][(256+tid)*8]);
    }
    // compute tile kiter from buf[cur]: 16 MFMA
    bf16x8 af_[4], bf_[4];
    #pragma unroll
    for (int fr = 0; fr < 4; ++fr)
      af_[fr] = *(const bf16x8*)&aT[cur][(lg*130 + wr*64 + fr*16 + l15)*8];
    #pragma unroll
    for (int cf = 0; cf < 4; ++cf)
      bf_[cf] = *(const bf16x8*)&bT[cur][(lg*128 + wc*64 + cf*16 + l15)*8];
    #pragma unroll
    for (int fr = 0; fr < 4; ++fr)
      #pragma unroll
      for (int cf = 0; cf < 4; ++cf)
        acc[fr][cf] = __builtin_amdgcn_mfma_f32_16x16x32_bf16(af_[fr], bf_[cf], acc[fr][cf], 0, 0, 0);
    // stage A tile kiter+1 and prefetch tile kiter+2
    if (kiter < 23) {
      unsigned p0 = cvt_pk_bf16(rA0.x, rA0.y), p1 = cvt_pk_bf16(rA0.z, rA0.w);
      unsigned p2 = cvt_pk_bf16(rA1.x, rA1.y), p3 = cvt_pk_bf16(rA1.z, rA1.w);
      unsigned p4 = cvt_pk_bf16(rA2.x, rA2.y), p5 = cvt_pk_bf16(rA2.z, rA2.w);
      unsigned p6 = cvt_pk_bf16(rA3.x, rA3.y), p7 = cvt_pk_bf16(rA3.z, rA3.w);
      *(uint4*)&aT[cur^1][aw0] = make_uint4(p0, p1, p2, p3);
      *(uint4*)&aT[cur^1][aw1] = make_uint4(p4, p5, p6, p7);
      if (kiter < 22) {
        const float* ap2 = aP + (kiter+2)*32;
        rA0 = *(const float4*)(ap2);
        rA1 = *(const float4*)(ap2 + 4);
        rA2 = *(const float4*)(ap2 + 8);
        rA3 = *(const float4*)(ap2 + 12);
      }
    }
    __syncthreads();
    cur ^= 1;
  }

  #pragma unroll
  for (int fr = 0; fr < 4; ++fr) {
    #pragma unroll
    for (int r4 = 0; r4 < 4; ++r4) {
      int rloc = wr*64 + fr*16 + lg*4 + r4;
      int rg = rowsS[rloc];
      if (rg < 0) continue;
      long obase = ((long)(rg >> 9) * 8) * 32768 + (long)(rg & 511) * 64;
      #pragma unroll
      for (int cf = 0; cf < 4; ++cf) {
        int c = wc*64 + cf*16 + l15;
        hp1b[obase + (long)(hb*2 + (c >> 6))*32768 + (c & 63)] = (u16)f2bf(acc[fr][cf][r4]);
      }
    }
  }
}

// ---------------------------------------------------------------------------
// K5: layer-2 gathered GEMM, bf16 MFMA. Flat 768-block grid. Reads xbf.
// ---------------------------------------------------------------------------
__global__ __launch_bounds__(256) void gemm2_mfma(
    const u16* __restrict__ xbf,
    const u16* __restrict__ w2t,
    const int* __restrict__ rowlist, const int* __restrict__ counts,
    float* __restrict__ hp2)
{
  int i   = blockIdx.x;           // 0..767
  int t   = i >> 8;
  int cnt = counts[t];
  int r0  = (i & 255) * 64;
  if (r0 >= cnt) return;

  __shared__ short aT[4*66*8];
  __shared__ short bT[4*66*8];
  __shared__ int rowsS[64];

  int tid = threadIdx.x;
  if (tid < 64) {
    int rr = r0 + tid;
    rowsS[tid] = (rr < cnt) ? rowlist[t*NROWS + rr] : -1;
  }
  __syncthreads();

  int ar = tid >> 2, ac = tid & 3;
  int sg = rowsS[ar]; if (sg < 0) sg = rowsS[0];
  long apart = ((long)(sg >> 9) * 8) * 32768 + (long)(sg & 511) * 64;

  int colb = tid >> 2, off = tid & 3;
  const u16* bP = w2t + ((long)t*64 + colb)*512;

  int wv = tid >> 6, l = tid & 63;
  int l15 = l & 15, lg = l >> 4;

  f32x4 acc[4];
  #pragma unroll
  for (int cf = 0; cf < 4; ++cf) acc[cf] = (f32x4){0.f,0.f,0.f,0.f};

  int ka0 = ac*8;
  bf16x8 ra = *(const bf16x8*)(xbf + apart + (long)(ka0 >> 6)*32768 + (ka0 & 63));
  bf16x8 rb = *(const bf16x8*)(bP + off*8);

  for (int k0 = 0; k0 < 512; k0 += 32) {
    __syncthreads();
    *(bf16x8*)&aT[(ac*66 + ar)*8]   = ra;
    *(bf16x8*)&bT[(off*66 + colb)*8] = rb;
    __syncthreads();
    if (k0 + 32 < 512) {
      int kn = k0 + 32 + ac*8;
      ra = *(const bf16x8*)(xbf + apart + (long)(kn >> 6)*32768 + (kn & 63));
      rb = *(const bf16x8*)(bP + k0 + 32 + off*8);
    }
    bf16x8 af, bfr[4];
    af = *(const bf16x8*)&aT[(lg*66 + wv*16 + l15)*8];
    #pragma unroll
    for (int cf = 0; cf < 4; ++cf)
      bfr[cf] = *(const bf16x8*)&bT[(lg*66 + cf*16 + l15)*8];
    #pragma unroll
    for (int cf = 0; cf < 4; ++cf)
      acc[cf] = __builtin_amdgcn_mfma_f32_16x16x32_bf16(af, bfr[cf], acc[cf], 0, 0, 0);
  }

  #pragma unroll
  for (int r4 = 0; r4 < 4; ++r4) {
    int rloc = wv*16 + lg*4 + r4;
    int rg = rowsS[rloc];
    if (rg < 0) continue;
    #pragma unroll
    for (int cf = 0; cf < 4; ++cf)
      hp2[(long)rg*64 + cf*16 + l15] = acc[cf][r4];
  }
}

// ---------------------------------------------------------------------------
// K4: GAT layer-1 attention. 512 blocks (2 per (b,h)), fp8 P/V LDS,
// pairwise no-max softmax with raw v_exp_f32 + log2e pre-scale, deferred
// rcp, fp8 PV MFMA. (unchanged — measured 62.4 us)
// ---------------------------------------------------------------------------
__global__ __launch_bounds__(1024) void gat1_attn(
    const u16* __restrict__ hp1b, const u64* __restrict__ maskw,
    const float* __restrict__ a_src, const float* __restrict__ a_dst,
    const float* __restrict__ b1, u16* __restrict__ xbf)
{
  extern __shared__ char smc[];
  char*  hpTf = smc;                          // [64 koct][66 o][8 kin] fp8  33,792
  char*  pSf  = smc + 33792;                  // [64 koct][66 row][8 kin] fp8 33,792
  float* srcS = (float*)(smc + 67584);        // [512]
  float* dstS = (float*)(smc + 69632);        // [512]
  float* asS  = (float*)(smc + 71680);        // [64]
  float* adS  = (float*)(smc + 71936);        // [64]
  float* rcpS = (float*)(smc + 72192);        // [64]   end 72,448

  const float LOG2E = 1.4426950408889634f;

  int bid = blockIdx.x;
  int bh = bid >> 1, qh = bid & 1;
  int b = bh >> 3, h = bh & 7;
  int tid = threadIdx.x;

  if (tid < 64) asS[tid] = a_src[h*64 + tid];
  else if (tid < 128) adS[tid - 64] = a_dst[h*64 + (tid - 64)];
  __syncthreads();

  {
    int m = tid >> 1, half = tid & 1;
    int koct = m >> 3, kin = m & 7;
    const u16* hpRow = hp1b + ((long)bh*NN + m)*64 + half*32;
    float ps = 0.f, pd = 0.f;
    #pragma unroll
    for (int qq = 0; qq < 4; ++qq) {
      bf16x8 hv = *(const bf16x8*)(hpRow + qq*8);
      int o0 = half*32 + qq*8;
      #pragma unroll
      for (int j = 0; j < 8; ++j) {
        float f = bf2f(hv[j]);
        ps += f * asS[o0 + j];
        pd += f * adS[o0 + j];
        hpTf[(koct*66 + o0 + j)*8 + kin] = (char)(cvt_pk_fp8(f, f) & 0xffu);
      }
    }
    ps += __shfl_xor(ps, 1);
    pd += __shfl_xor(pd, 1);
    if ((tid & 1) == 0) { srcS[m] = ps * LOG2E; dstS[m] = pd * LOG2E; }
  }
  __syncthreads();

  int wv = tid >> 6, lane = tid & 63;
  int l15 = lane & 15, lg = lane >> 4;
  int cgl = wv >> 2, nt = wv & 3;
  int o_out = nt*16 + l15;
  float bb  = b1[o_out];

  float2 dst2[4];
  #pragma unroll
  for (int jj = 0; jj < 4; ++jj)
    dst2[jj] = *(const float2*)&dstS[jj*128 + 2*lane];
  int wsel = lane >> 5;
  unsigned sh = (unsigned)((2*lane) & 63);
  int pbase = ((lane >> 2)*66)*8 + 2*(lane & 3);

  for (int s = 0; s < 4; ++s) {
    int sup = qh*4 + s;
    #pragma unroll
    for (int rr = 0; rr < 4; ++rr) {
      int rloc = wv*4 + rr;
      int row  = sup*64 + rloc;
      float srcv = srcS[row];
      const u64* mrow = maskw + ((long)(b*NN + row))*8;
      float lsum = 0.f;
      #pragma unroll
      for (int jj = 0; jj < 4; ++jj) {
        u64 w = mrow[jj*2 + wsel];
        unsigned bits = (unsigned)(w >> sh) & 3u;
        float s0 = srcv + dst2[jj].x;
        float s1 = srcv + dst2[jj].y;
        float p0 = (bits & 1u) ? exp2_fast(lrelu_f(s0)) : 0.f;
        float p1 = (bits & 2u) ? exp2_fast(lrelu_f(s1)) : 0.f;
        lsum += p0 + p1;
        *(u16*)&pSf[(jj*16*66)*8 + pbase + rloc*8] = (u16)cvt_pk_fp8(p0, p1);
      }
      #pragma unroll
      for (int mk = 1; mk <= 32; mk <<= 1) lsum += __shfl_xor(lsum, mk);
      if (lane == 0) rcpS[rloc] = 1.f / lsum;
    }
    __syncthreads();

    f32x4 acc = {0.f, 0.f, 0.f, 0.f};
    #pragma unroll
    for (int ks = 0; ks < 16; ++ks) {
      int koct = ks*4 + lg;
      i64 af = *(const i64*)&pSf [(koct*66 + cgl*16 + l15)*8];
      i64 bf = *(const i64*)&hpTf[(koct*66 + nt*16  + l15)*8];
      acc = __builtin_amdgcn_mfma_f32_16x16x32_fp8_fp8(af, bf, acc, 0, 0, 0);
    }
    #pragma unroll
    for (int reg = 0; reg < 4; ++reg) {
      int rloc = cgl*16 + lg*4 + reg;
      int row  = sup*64 + rloc;
      float v = elu_f(acc[reg] * rcpS[rloc] + bb);
      xbf[((long)bh*NN + row)*64 + o_out] = (u16)f2bf(v);
    }
    __syncthreads();
  }
}

// ---------------------------------------------------------------------------
// K6: GAT layer-2 attention (rows 0,1 only) + ELU + MLP + log_softmax.
// ---------------------------------------------------------------------------
__global__ __launch_bounds__(256) void gat2_final(
    const float* __restrict__ hp2, const u64* __restrict__ maskw,
    const float* __restrict__ a_src2, const float* __restrict__ a_dst2,
    const float* __restrict__ b2,
    const float* __restrict__ fc1_w, const float* __restrict__ fc1_b,
    const float* __restrict__ fc2_w, const float* __restrict__ fc2_b,
    const float* __restrict__ fc3_w, const float* __restrict__ fc3_b,
    float* __restrict__ out)
{
  extern __shared__ float sm[];
  float* hpS  = sm;              // 32768
  float* dstS = hpS + 32768;     // 512
  float* srcS = dstS + 512;      // 512
  float* pS   = srcS + 512;      // 512
  float* redS = pS + 512;        // 256
  float* outS = redS + 256;      // 128
  float* vS   = outS + 128;      // 64
  float* y1S  = vS + 64;         // 192
  float* redM = y1S + 192;       // 8
  float4* hpS4 = (float4*)hpS;

  int b = blockIdx.x;
  int tid = threadIdx.x;
  int og = tid & 15, m16 = tid >> 4;

  for (int it = 0; it < 32; ++it) {
    int fi = it*256 + tid;
    int m = fi >> 4, o4 = fi & 15;
    hpS4[m*16 + o4] = *(const float4*)(hp2 + (long)(b*NN + m)*64 + o4*4);
  }
  __syncthreads();

  float4 as4 = *(const float4*)(a_src2 + og*4);
  float4 ad4 = *(const float4*)(a_dst2 + og*4);
  for (int it = 0; it < 32; ++it) {
    int m = it*16 + m16;
    float4 hv = hpS4[m*16 + og];
    float ls = hv.x*as4.x + hv.y*as4.y + hv.z*as4.z + hv.w*as4.w;
    float ld = hv.x*ad4.x + hv.y*ad4.y + hv.z*ad4.z + hv.w*ad4.w;
    #pragma unroll
    for (int mk = 1; mk <= 8; mk <<= 1) {
      ls += __shfl_xor(ls, mk);
      ld += __shfl_xor(ld, mk);
    }
    if (og == 0) { srcS[m] = ls; dstS[m] = ld; }
  }
  __syncthreads();

  for (int n = 0; n < 2; ++n) {
    float srcv = srcS[n];
    const u64* mrow = maskw + (long)(b*NN + n)*8;
    int m0 = tid, m1 = tid + 256;
    u64 w0 = mrow[m0 >> 6], w1 = mrow[m1 >> 6];
    float s0 = srcv + dstS[m0], s1 = srcv + dstS[m1];
    float e0 = ((w0 >> (m0 & 63)) & 1ull) ? lrelu_f(s0) : -1.0e9f;
    float e1 = ((w1 >> (m1 & 63)) & 1ull) ? lrelu_f(s1) : -1.0e9f;
    float emax = fmaxf(e0, e1);
    #pragma unroll
    for (int mk = 1; mk <= 32; mk <<= 1) emax = fmaxf(emax, __shfl_xor(emax, mk));
    if ((tid & 63) == 0) redM[tid >> 6] = emax;
    __syncthreads();
    emax = fmaxf(fmaxf(redM[0], redM[1]), fmaxf(redM[2], redM[3]));
    float p0 = __expf(e0 - emax), p1 = __expf(e1 - emax);
    pS[m0] = p0; pS[m1] = p1;
    float lsum = p0 + p1;
    #pragma unroll
    for (int mk = 1; mk <= 32; mk <<= 1) lsum += __shfl_xor(lsum, mk);
    if ((tid & 63) == 0) redM[4 + (tid >> 6)] = lsum;
    __syncthreads();
    float rcp = 1.f / (redM[4] + redM[5] + redM[6] + redM[7]);

    float4 acc = make_float4(0.f,0.f,0.f,0.f);
    for (int mm = 0; mm < 32; ++mm) {
      int m = mm*16 + m16;
      float4 hv = hpS4[m*16 + og];
      float p = pS[m];
      acc.x += hv.x*p; acc.y += hv.y*p; acc.z += hv.z*p; acc.w += hv.w*p;
    }
    acc.x += __shfl_xor(acc.x, 16); acc.y += __shfl_xor(acc.y, 16);
    acc.z += __shfl_xor(acc.z, 16); acc.w += __shfl_xor(acc.w, 16);
    acc.x += __shfl_xor(acc.x, 32); acc.y += __shfl_xor(acc.y, 32);
    acc.z += __shfl_xor(acc.z, 32); acc.w += __shfl_xor(acc.w, 32);
    __syncthreads();
    if ((tid & 63) < 16) ((float4*)redS)[(tid >> 6)*16 + (tid & 15)] = acc;
    __syncthreads();
    if (tid < 16) {
      float4 s = make_float4(0.f,0.f,0.f,0.f);
      #pragma unroll
      for (int w = 0; w < 4; ++w) {
        float4 v = ((float4*)redS)[w*16 + tid];
        s.x += v.x; s.y += v.y; s.z += v.z; s.w += v.w;
      }
      float4 bv = *(const float4*)(b2 + tid*4);
      outS[n*64 + tid*4 + 0] = elu_f(s.x*rcp + bv.x);
      outS[n*64 + tid*4 + 1] = elu_f(s.y*rcp + bv.y);
      outS[n*64 + tid*4 + 2] = elu_f(s.z*rcp + bv.z);
      outS[n*64 + tid*4 + 3] = elu_f(s.w*rcp + bv.w);
    }
    __syncthreads();
  }

  if (tid < 64) vS[tid] = outS[tid] * outS[64 + tid];
  __syncthreads();
  if (tid < 192) {
    float a = fc1_b[tid];
    for (int o = 0; o < 64; ++o) a += vS[o]*fc1_w[o*192 + tid];
    y1S[tid] = a > 0.f ? a : 0.f;
  }
  __syncthreads();
  if (tid < 64) {
    float a = fc2_b[tid];
    for (int j = 0; j < 192; ++j) a += y1S[j]*fc2_w[j*64 + tid];
    vS[tid] = a > 0.f ? a : 0.f;
  }
  __syncthreads();
  if (tid == 0) {
    float t0 = fc3_b[0], t1 = fc3_b[1];
    for (int k = 0; k < 64; ++k) {
      float y = vS[k];
      t0 += y*fc3_w[k*2 + 0];
      t1 += y*fc3_w[k*2 + 1];
    }
    float mx = fmaxf(t0, t1);
    float lse = mx + logf(__expf(t0 - mx) + __expf(t1 - mx));
    out[b*2 + 0] = t0 - lse;
    out[b*2 + 1] = t1 - lse;
  }
}

// ---------------------------------------------------------------------------
extern "C" void kernel_launch(void* const* d_in, const int* in_sizes, int n_in,
                              void* d_out, int out_size, void* d_ws, size_t ws_size,
                              hipStream_t stream) {
  const float* emb    = (const float*)d_in[0];
  const int*   adj    = (const int*)d_in[1];
  const float* vt     = (const float*)d_in[2];
  const float* w1     = (const float*)d_in[3];
  const float* a_src1 = (const float*)d_in[4];
  const float* a_dst1 = (const float*)d_in[5];
  const float* b1     = (const float*)d_in[6];
  const float* w2     = (const float*)d_in[7];
  const float* a_src2 = (const float*)d_in[8];
  const float* a_dst2 = (const float*)d_in[9];
  const float* b2     = (const float*)d_in[10];
  const float* fc1_w  = (const float*)d_in[11];
  const float* fc1_b  = (const float*)d_in[12];
  const float* fc2_w  = (const float*)d_in[13];
  const float* fc2_b  = (const float*)d_in[14];
  const float* fc3_w  = (const float*)d_in[15];
  const float* fc3_b  = (const float*)d_in[16];

  char* ws = (char*)d_ws;
  int* counts  = (int*)ws;
  int* rowlist = (int*)(ws + 4096);
  u64* maskw   = (u64*)(ws + 204800);
  u16* w2t     = (u16*)(ws + 3670016);
  u16* hp1b    = (u16*)(ws + 3932160);           // 16.78 MB
  float* hp2   = (float*)(ws + 20709376);        // 4.19 MB
  u16* w1tt    = (u16*)(ws + 1310720);           // 2.36 MB (old w1t slot)
  u16* xbf     = (u16*)(ws + 24903680);          // 16.78 MB -> end 41.7 MB

  hipMemsetAsync(counts, 0, 16, stream);
  prep_kernel<<<NROWS/4, 256, 0, stream>>>(adj, maskw);
  rowlist_kernel<<<NROWS/256, 256, 0, stream>>>(vt, rowlist, counts);
  conv_w<<<dim3(27, 4), 256, 0, stream>>>(w1, w2, w1tt, w2t);

  gemm1_mfma<<<dim3(516), 256, 0, stream>>>(emb, w1tt, rowlist, counts, hp1b);

  size_t sm1 = 72448;
  gat1_attn<<<BB*NH*2, 1024, sm1, stream>>>(hp1b, maskw, a_src1, a_dst1, b1, xbf);

  gemm2_mfma<<<dim3(768), 256, 0, stream>>>(xbf, w2t, rowlist, counts, hp2);

  size_t sm2 = (size_t)(32768 + 512 + 512 + 512 + 256 + 128 + 64 + 192 + 8) * 4;
  gat2_final<<<BB, 256, sm2, stream>>>(hp2, maskw, a_src2, a_dst2, b2,
                                       fc1_w, fc1_b, fc2_w, fc2_b, fc3_w, fc3_b,
                                       (float*)d_out);
}

// Round 18
// 139.404 us; speedup vs baseline: 1.1243x; 1.1243x over previous
//
#include <hip/hip_runtime.h>

#define BB   32
#define NN   512
#define NH   8
#define FIN  768
#define FHID 64
#define NROWS (BB*NN)   // 16384

typedef __attribute__((ext_vector_type(8))) short bf16x8;
typedef __attribute__((ext_vector_type(4))) short s16x4;
typedef __attribute__((ext_vector_type(4))) float f32x4;
typedef unsigned long long u64;
typedef unsigned short u16;
typedef long i64;

__device__ __forceinline__ float lrelu_f(float s){ return fmaxf(s, 0.2f*s); }
__device__ __forceinline__ float elu_f(float s){ return s > 0.f ? s : expm1f(s); }
__device__ __forceinline__ short f2bf(float f){
  unsigned u = __float_as_uint(f);
  return (short)((u + 0x7fffu + ((u >> 16) & 1u)) >> 16);   // RNE
}
__device__ __forceinline__ float bf2f(short s){
  return __uint_as_float(((unsigned)(u16)s) << 16);
}
// packed {bf16(lo), bf16(hi)} in one u32 — single VOP3 (RNE)
__device__ __forceinline__ unsigned cvt_pk_bf16(float lo, float hi){
  unsigned r;
  asm("v_cvt_pk_bf16_f32 %0, %1, %2" : "=v"(r) : "v"(lo), "v"(hi));
  return r;
}
// raw HW 2^x (1 instruction; very negative input -> 0)
__device__ __forceinline__ float exp2_fast(float x){
  float r;
  asm("v_exp_f32 %0, %1" : "=v"(r) : "v"(x));
  return r;
}
// packed {fp8(lo), fp8(hi)} in low 16 bits (OCP e4m3)
__device__ __forceinline__ unsigned cvt_pk_fp8(float lo, float hi){
  return (unsigned)__builtin_amdgcn_cvt_pk_fp8_f32(lo, hi, 0, false);
}
// async global->LDS DMA, 16B per lane (wave-uniform LDS base + lane*16)
__device__ __forceinline__ void gll16(const void* g, void* l){
  __builtin_amdgcn_global_load_lds(
      (const __attribute__((address_space(1))) void*)g,
      (__attribute__((address_space(3))) void*)l, 16, 0, 0);
}

// ---------------------------------------------------------------------------
// K1 (fused front): blocks [0..107] = conv_w (27 mats x 4 K-quarters),
// [108..171] = rowlist, [172..4267] = prep (adjacency bitmasks).
// The three tasks are mutually independent; fusing removes 2 launch gaps
// and overlaps their memory phases. conv blocks dispatched FIRST so the
// gemm1-feeding path (w1t -> retile -> gemm1) drains earliest.
// Bodies are byte-identical to the round-16 kernels.
// ---------------------------------------------------------------------------
__global__ __launch_bounds__(256) void front_kernel(
    const int* __restrict__ adj, const float* __restrict__ vt,
    const float* __restrict__ w1, const float* __restrict__ w2,
    u64* __restrict__ maskw, int* __restrict__ rowlist, int* __restrict__ counts,
    u16* __restrict__ w1t, u16* __restrict__ w2t)
{
  __shared__ float tile[64][68];      // used by conv part only
  __shared__ int lc[3];
  __shared__ int lbase[3];
  int gb = blockIdx.x;
  int tid = threadIdx.x;

  if (gb < 108) {
    // ---- conv_w: weight transpose+cast ----
    int bid = gb % 27, kq = gb / 27;
    const float* src; u16* dst; int K;
    if (bid < 24) { src = w1 + (long)bid*768*64; dst = w1t + (long)bid*64*768; K = 768; }
    else { int t = bid - 24; src = w2 + (long)t*512*64; dst = w2t + (long)t*64*512; K = 512; }
    int kstart = kq * (K >> 2), kend = kstart + (K >> 2);
    for (int k0 = kstart; k0 < kend; k0 += 64) {
      __syncthreads();
      #pragma unroll
      for (int i = 0; i < 4; ++i) {
        int kk = i*16 + (tid >> 4);
        int oo = (tid & 15) * 4;
        float4 v = *(const float4*)(src + (long)(k0 + kk)*64 + oo);
        *(float4*)&tile[kk][oo] = v;
      }
      __syncthreads();
      int o = tid >> 2, kp = (tid & 3) * 16;
      unsigned pk[8];
      #pragma unroll
      for (int j = 0; j < 8; ++j)
        pk[j] = cvt_pk_bf16(tile[kp + 2*j][o], tile[kp + 2*j + 1][o]);
      u16* d = dst + (long)o*K + k0 + kp;
      #pragma unroll
      for (int j = 0; j < 8; ++j) *(unsigned*)(d + 2*j) = pk[j];
    }
  } else if (gb < 172) {
    // ---- rowlist: per-type gathered row lists ----
    int row = (gb - 108) * 256 + tid;
    if (tid < 3) lc[tid] = 0;
    __syncthreads();
    const float* v = vt + (long)row*3;
    int t = v[1] > 0.5f ? 1 : (v[2] > 0.5f ? 2 : 0);
    int p = atomicAdd(&lc[t], 1);
    __syncthreads();
    if (tid < 3) lbase[tid] = atomicAdd(&counts[tid], lc[tid]);
    __syncthreads();
    rowlist[t*NROWS + lbase[t] + p] = row;
  } else {
    // ---- prep: adjacency -> bitmask words ----
    int row  = (gb - 172) * 4 + (tid >> 6);
    int lane = tid & 63;
    const int* arow = adj + (long)row * NN;
    #pragma unroll
    for (int w = 0; w < 8; ++w) {
      u64 bal = __ballot(arow[w*64 + lane] > 0);
      if (lane == 0) maskw[(long)row*8 + w] = bal;
    }
  }
}

// ---------------------------------------------------------------------------
// K2b: retile w1t into gemm1's LDS image order (round-16 version):
// w1tt[(t*4+hb)][kiter 0..23][kg 0..3][col 0..127][8] — contiguous 8KB chunks.
// ---------------------------------------------------------------------------
__global__ __launch_bounds__(256) void retile_w1(
    const u16* __restrict__ w1t, u16* __restrict__ w1tt)
{
  int thb = blockIdx.x;      // 0..11 = t*4 + hb
  int kiter = blockIdx.y;    // 0..23
  int t = thb >> 2, hb = thb & 3;
  int tid = threadIdx.x;
  u16* dst = w1tt + ((long)thb*24 + kiter)*4096;
  #pragma unroll
  for (int c = 0; c < 2; ++c) {
    int u = c*256 + tid;               // 0..511
    int kg = u >> 7, col = u & 127;
    int head = hb*2 + (col >> 6), o = col & 63;
    int k = kiter*32 + kg*8;
    const u16* s = w1t + (((long)t*8 + head)*64 + o)*768 + k;
    *(bf16x8*)(dst + u*8) = *(const bf16x8*)s;
  }
}

// ---------------------------------------------------------------------------
// K3: layer-1 gathered GEMM, bf16 MFMA. Round-16 version (REVERTED from
// round-17's BM=128, which regressed +13us and shifted absmax): BM=64,
// BN=128, 4 waves, B staged via global_load_lds DMA from w1tt chunks,
// A reg-staged with cvt_pk, one barrier/iter.
// ---------------------------------------------------------------------------
__global__ __launch_bounds__(256) void gemm1_mfma(
    const float* __restrict__ emb,
    const u16* __restrict__ w1tt,
    const int* __restrict__ rowlist, const int* __restrict__ counts,
    u16* __restrict__ hp1b)
{
  int i   = blockIdx.x;           // 0..1055
  int t   = i / 352;
  int r   = i - t*352;
  int cnt = counts[t];
  int xcd = r & 7;
  int q   = r >> 3;
  int hb  = q & 3;
  int rb  = (q >> 2) * 8 + xcd;
  int r0  = rb * 64;
  if (r0 >= cnt) return;

  __shared__ short aT[2][4*66*8];     // [kg][66 rows][8]
  __shared__ short bT[2][4096];       // [kg][128 col][8], linear (DMA dest)
  __shared__ int rowsS[64];

  int tid = threadIdx.x;
  if (tid < 64) {
    int rr = r0 + tid;
    rowsS[tid] = (rr < cnt) ? rowlist[t*NROWS + rr] : -1;
  }
  __syncthreads();

  int ar = tid >> 2, ac = tid & 3;
  int sg = rowsS[ar]; if (sg < 0) sg = rowsS[0];
  const float* aP = emb + (long)sg*768;

  const u16* bBase = w1tt + ((long)(t*4 + hb)*24)*4096;

  int wv = tid >> 6, l = tid & 63;
  int wr = wv >> 1, wc = wv & 1;
  int l15 = l & 15, lg = l >> 4;

  int aw0 = (( (ac>>1)     )*66 + ar)*8 + (ac&1)*4;
  int aw1 = (( 2 + (ac>>1) )*66 + ar)*8 + (ac&1)*4;

  f32x4 acc[2][4];
  #pragma unroll
  for (int fr = 0; fr < 2; ++fr)
    #pragma unroll
    for (int cf = 0; cf < 4; ++cf) acc[fr][cf] = (f32x4){0.f,0.f,0.f,0.f};

  // prologue: DMA B tile0 -> bT[0]; A tile0 -> aT[0]; prefetch A tile1 regs
  gll16(bBase + tid*8,        &bT[0][tid*8]);
  gll16(bBase + (256+tid)*8,  &bT[0][(256+tid)*8]);
  float4 rA0 = *(const float4*)(aP + ac*4);
  float4 rA1 = *(const float4*)(aP + 16 + ac*4);
  {
    unsigned lo0 = cvt_pk_bf16(rA0.x, rA0.y), hi0 = cvt_pk_bf16(rA0.z, rA0.w);
    unsigned lo1 = cvt_pk_bf16(rA1.x, rA1.y), hi1 = cvt_pk_bf16(rA1.z, rA1.w);
    *(uint2*)&aT[0][aw0] = make_uint2(lo0, hi0);
    *(uint2*)&aT[0][aw1] = make_uint2(lo1, hi1);
  }
  rA0 = *(const float4*)(aP + 32 + ac*4);
  rA1 = *(const float4*)(aP + 48 + ac*4);
  __syncthreads();   // drains DMA (vmcnt) + publishes aT[0]

  int cur = 0;
  for (int kiter = 0; kiter < 24; ++kiter) {
    if (kiter < 23) {          // DMA B tile kiter+1 into free buffer
      const u16* bsrc = bBase + (long)(kiter+1)*4096;
      gll16(bsrc + tid*8,       &bT[cur^1][tid*8]);
      gll16(bsrc + (256+tid)*8, &bT[cur^1][(256+tid)*8]);
    }
    // compute tile kiter from buf[cur]
    bf16x8 af_[2], bf_[4];
    #pragma unroll
    for (int fr = 0; fr < 2; ++fr)
      af_[fr] = *(const bf16x8*)&aT[cur][(lg*66 + wr*32 + fr*16 + l15)*8];
    #pragma unroll
    for (int cf = 0; cf < 4; ++cf)
      bf_[cf] = *(const bf16x8*)&bT[cur][(lg*128 + wc*64 + cf*16 + l15)*8];
    #pragma unroll
    for (int fr = 0; fr < 2; ++fr)
      #pragma unroll
      for (int cf = 0; cf < 4; ++cf)
        acc[fr][cf] = __builtin_amdgcn_mfma_f32_16x16x32_bf16(af_[fr], bf_[cf], acc[fr][cf], 0, 0, 0);
    // stage A tile kiter+1 (in rA) and prefetch tile kiter+2
    if (kiter < 23) {
      unsigned lo0 = cvt_pk_bf16(rA0.x, rA0.y), hi0 = cvt_pk_bf16(rA0.z, rA0.w);
      unsigned lo1 = cvt_pk_bf16(rA1.x, rA1.y), hi1 = cvt_pk_bf16(rA1.z, rA1.w);
      *(uint2*)&aT[cur^1][aw0] = make_uint2(lo0, hi0);
      *(uint2*)&aT[cur^1][aw1] = make_uint2(lo1, hi1);
      if (kiter < 22) {
        rA0 = *(const float4*)(aP + (kiter+2)*32 + ac*4);
        rA1 = *(const float4*)(aP + (kiter+2)*32 + 16 + ac*4);
      }
    }
    __syncthreads();
    cur ^= 1;
  }

  #pragma unroll
  for (int fr = 0; fr < 2; ++fr) {
    #pragma unroll
    for (int r4 = 0; r4 < 4; ++r4) {
      int rloc = wr*32 + fr*16 + lg*4 + r4;
      int rg = rowsS[rloc];
      if (rg < 0) continue;
      long obase = ((long)(rg >> 9) * 8) * 32768 + (long)(rg & 511) * 64;
      #pragma unroll
      for (int cf = 0; cf < 4; ++cf) {
        int c = wc*64 + cf*16 + l15;
        hp1b[obase + (long)(hb*2 + (c >> 6))*32768 + (c & 63)] = (u16)f2bf(acc[fr][cf][r4]);
      }
    }
  }
}

// ---------------------------------------------------------------------------
// K5: layer-2 gathered GEMM, bf16 MFMA. Flat 768-block grid. Reads xbf.
// ---------------------------------------------------------------------------
__global__ __launch_bounds__(256) void gemm2_mfma(
    const u16* __restrict__ xbf,
    const u16* __restrict__ w2t,
    const int* __restrict__ rowlist, const int* __restrict__ counts,
    float* __restrict__ hp2)
{
  int i   = blockIdx.x;           // 0..767
  int t   = i >> 8;
  int cnt = counts[t];
  int r0  = (i & 255) * 64;
  if (r0 >= cnt) return;

  __shared__ short aT[4*66*8];
  __shared__ short bT[4*66*8];
  __shared__ int rowsS[64];

  int tid = threadIdx.x;
  if (tid < 64) {
    int rr = r0 + tid;
    rowsS[tid] = (rr < cnt) ? rowlist[t*NROWS + rr] : -1;
  }
  __syncthreads();

  int ar = tid >> 2, ac = tid & 3;
  int sg = rowsS[ar]; if (sg < 0) sg = rowsS[0];
  long apart = ((long)(sg >> 9) * 8) * 32768 + (long)(sg & 511) * 64;

  int colb = tid >> 2, off = tid & 3;
  const u16* bP = w2t + ((long)t*64 + colb)*512;

  int wv = tid >> 6, l = tid & 63;
  int l15 = l & 15, lg = l >> 4;

  f32x4 acc[4];
  #pragma unroll
  for (int cf = 0; cf < 4; ++cf) acc[cf] = (f32x4){0.f,0.f,0.f,0.f};

  int ka0 = ac*8;
  bf16x8 ra = *(const bf16x8*)(xbf + apart + (long)(ka0 >> 6)*32768 + (ka0 & 63));
  bf16x8 rb = *(const bf16x8*)(bP + off*8);

  for (int k0 = 0; k0 < 512; k0 += 32) {
    __syncthreads();
    *(bf16x8*)&aT[(ac*66 + ar)*8]   = ra;
    *(bf16x8*)&bT[(off*66 + colb)*8] = rb;
    __syncthreads();
    if (k0 + 32 < 512) {
      int kn = k0 + 32 + ac*8;
      ra = *(const bf16x8*)(xbf + apart + (long)(kn >> 6)*32768 + (kn & 63));
      rb = *(const bf16x8*)(bP + k0 + 32 + off*8);
    }
    bf16x8 af, bfr[4];
    af = *(const bf16x8*)&aT[(lg*66 + wv*16 + l15)*8];
    #pragma unroll
    for (int cf = 0; cf < 4; ++cf)
      bfr[cf] = *(const bf16x8*)&bT[(lg*66 + cf*16 + l15)*8];
    #pragma unroll
    for (int cf = 0; cf < 4; ++cf)
      acc[cf] = __builtin_amdgcn_mfma_f32_16x16x32_bf16(af, bfr[cf], acc[cf], 0, 0, 0);
  }

  #pragma unroll
  for (int r4 = 0; r4 < 4; ++r4) {
    int rloc = wv*16 + lg*4 + r4;
    int rg = rowsS[rloc];
    if (rg < 0) continue;
    #pragma unroll
    for (int cf = 0; cf < 4; ++cf)
      hp2[(long)rg*64 + cf*16 + l15] = acc[cf][r4];
  }
}

// ---------------------------------------------------------------------------
// K4: GAT layer-1 attention. 512 blocks (2 per (b,h)), fp8 P/V LDS,
// pairwise no-max softmax with raw v_exp_f32 + log2e pre-scale, deferred
// rcp, fp8 PV MFMA. (unchanged — measured 62.4 us)
// ---------------------------------------------------------------------------
__global__ __launch_bounds__(1024) void gat1_attn(
    const u16* __restrict__ hp1b, const u64* __restrict__ maskw,
    const float* __restrict__ a_src, const float* __restrict__ a_dst,
    const float* __restrict__ b1, u16* __restrict__ xbf)
{
  extern __shared__ char smc[];
  char*  hpTf = smc;                          // [64 koct][66 o][8 kin] fp8  33,792
  char*  pSf  = smc + 33792;                  // [64 koct][66 row][8 kin] fp8 33,792
  float* srcS = (float*)(smc + 67584);        // [512]
  float* dstS = (float*)(smc + 69632);        // [512]
  float* asS  = (float*)(smc + 71680);        // [64]
  float* adS  = (float*)(smc + 71936);        // [64]
  float* rcpS = (float*)(smc + 72192);        // [64]   end 72,448

  const float LOG2E = 1.4426950408889634f;

  int bid = blockIdx.x;
  int bh = bid >> 1, qh = bid & 1;
  int b = bh >> 3, h = bh & 7;
  int tid = threadIdx.x;

  if (tid < 64) asS[tid] = a_src[h*64 + tid];
  else if (tid < 128) adS[tid - 64] = a_dst[h*64 + (tid - 64)];
  __syncthreads();

  {
    int m = tid >> 1, half = tid & 1;
    int koct = m >> 3, kin = m & 7;
    const u16* hpRow = hp1b + ((long)bh*NN + m)*64 + half*32;
    float ps = 0.f, pd = 0.f;
    #pragma unroll
    for (int qq = 0; qq < 4; ++qq) {
      bf16x8 hv = *(const bf16x8*)(hpRow + qq*8);
      int o0 = half*32 + qq*8;
      #pragma unroll
      for (int j = 0; j < 8; ++j) {
        float f = bf2f(hv[j]);
        ps += f * asS[o0 + j];
        pd += f * adS[o0 + j];
        hpTf[(koct*66 + o0 + j)*8 + kin] = (char)(cvt_pk_fp8(f, f) & 0xffu);
      }
    }
    ps += __shfl_xor(ps, 1);
    pd += __shfl_xor(pd, 1);
    if ((tid & 1) == 0) { srcS[m] = ps * LOG2E; dstS[m] = pd * LOG2E; }
  }
  __syncthreads();

  int wv = tid >> 6, lane = tid & 63;
  int l15 = lane & 15, lg = lane >> 4;
  int cgl = wv >> 2, nt = wv & 3;
  int o_out = nt*16 + l15;
  float bb  = b1[o_out];

  float2 dst2[4];
  #pragma unroll
  for (int jj = 0; jj < 4; ++jj)
    dst2[jj] = *(const float2*)&dstS[jj*128 + 2*lane];
  int wsel = lane >> 5;
  unsigned sh = (unsigned)((2*lane) & 63);
  int pbase = ((lane >> 2)*66)*8 + 2*(lane & 3);

  for (int s = 0; s < 4; ++s) {
    int sup = qh*4 + s;
    #pragma unroll
    for (int rr = 0; rr < 4; ++rr) {
      int rloc = wv*4 + rr;
      int row  = sup*64 + rloc;
      float srcv = srcS[row];
      const u64* mrow = maskw + ((long)(b*NN + row))*8;
      float lsum = 0.f;
      #pragma unroll
      for (int jj = 0; jj < 4; ++jj) {
        u64 w = mrow[jj*2 + wsel];
        unsigned bits = (unsigned)(w >> sh) & 3u;
        float s0 = srcv + dst2[jj].x;
        float s1 = srcv + dst2[jj].y;
        float p0 = (bits & 1u) ? exp2_fast(lrelu_f(s0)) : 0.f;
        float p1 = (bits & 2u) ? exp2_fast(lrelu_f(s1)) : 0.f;
        lsum += p0 + p1;
        *(u16*)&pSf[(jj*16*66)*8 + pbase + rloc*8] = (u16)cvt_pk_fp8(p0, p1);
      }
      #pragma unroll
      for (int mk = 1; mk <= 32; mk <<= 1) lsum += __shfl_xor(lsum, mk);
      if (lane == 0) rcpS[rloc] = 1.f / lsum;
    }
    __syncthreads();

    f32x4 acc = {0.f, 0.f, 0.f, 0.f};
    #pragma unroll
    for (int ks = 0; ks < 16; ++ks) {
      int koct = ks*4 + lg;
      i64 af = *(const i64*)&pSf [(koct*66 + cgl*16 + l15)*8];
      i64 bf = *(const i64*)&hpTf[(koct*66 + nt*16  + l15)*8];
      acc = __builtin_amdgcn_mfma_f32_16x16x32_fp8_fp8(af, bf, acc, 0, 0, 0);
    }
    #pragma unroll
    for (int reg = 0; reg < 4; ++reg) {
      int rloc = cgl*16 + lg*4 + reg;
      int row  = sup*64 + rloc;
      float v = elu_f(acc[reg] * rcpS[rloc] + bb);
      xbf[((long)bh*NN + row)*64 + o_out] = (u16)f2bf(v);
    }
    __syncthreads();
  }
}

// ---------------------------------------------------------------------------
// K6: GAT layer-2 attention (rows 0,1 only) + ELU + MLP + log_softmax.
// ---------------------------------------------------------------------------
__global__ __launch_bounds__(256) void gat2_final(
    const float* __restrict__ hp2, const u64* __restrict__ maskw,
    const float* __restrict__ a_src2, const float* __restrict__ a_dst2,
    const float* __restrict__ b2,
    const float* __restrict__ fc1_w, const float* __restrict__ fc1_b,
    const float* __restrict__ fc2_w, const float* __restrict__ fc2_b,
    const float* __restrict__ fc3_w, const float* __restrict__ fc3_b,
    float* __restrict__ out)
{
  extern __shared__ float sm[];
  float* hpS  = sm;              // 32768
  float* dstS = hpS + 32768;     // 512
  float* srcS = dstS + 512;      // 512
  float* pS   = srcS + 512;      // 512
  float* redS = pS + 512;        // 256
  float* outS = redS + 256;      // 128
  float* vS   = outS + 128;      // 64
  float* y1S  = vS + 64;         // 192
  float* redM = y1S + 192;       // 8
  float4* hpS4 = (float4*)hpS;

  int b = blockIdx.x;
  int tid = threadIdx.x;
  int og = tid & 15, m16 = tid >> 4;

  for (int it = 0; it < 32; ++it) {
    int fi = it*256 + tid;
    int m = fi >> 4, o4 = fi & 15;
    hpS4[m*16 + o4] = *(const float4*)(hp2 + (long)(b*NN + m)*64 + o4*4);
  }
  __syncthreads();

  float4 as4 = *(const float4*)(a_src2 + og*4);
  float4 ad4 = *(const float4*)(a_dst2 + og*4);
  for (int it = 0; it < 32; ++it) {
    int m = it*16 + m16;
    float4 hv = hpS4[m*16 + og];
    float ls = hv.x*as4.x + hv.y*as4.y + hv.z*as4.z + hv.w*as4.w;
    float ld = hv.x*ad4.x + hv.y*ad4.y + hv.z*ad4.z + hv.w*ad4.w;
    #pragma unroll
    for (int mk = 1; mk <= 8; mk <<= 1) {
      ls += __shfl_xor(ls, mk);
      ld += __shfl_xor(ld, mk);
    }
    if (og == 0) { srcS[m] = ls; dstS[m] = ld; }
  }
  __syncthreads();

  for (int n = 0; n < 2; ++n) {
    float srcv = srcS[n];
    const u64* mrow = maskw + (long)(b*NN + n)*8;
    int m0 = tid, m1 = tid + 256;
    u64 w0 = mrow[m0 >> 6], w1 = mrow[m1 >> 6];
    float s0 = srcv + dstS[m0], s1 = srcv + dstS[m1];
    float e0 = ((w0 >> (m0 & 63)) & 1ull) ? lrelu_f(s0) : -1.0e9f;
    float e1 = ((w1 >> (m1 & 63)) & 1ull) ? lrelu_f(s1) : -1.0e9f;
    float emax = fmaxf(e0, e1);
    #pragma unroll
    for (int mk = 1; mk <= 32; mk <<= 1) emax = fmaxf(emax, __shfl_xor(emax, mk));
    if ((tid & 63) == 0) redM[tid >> 6] = emax;
    __syncthreads();
    emax = fmaxf(fmaxf(redM[0], redM[1]), fmaxf(redM[2], redM[3]));
    float p0 = __expf(e0 - emax), p1 = __expf(e1 - emax);
    pS[m0] = p0; pS[m1] = p1;
    float lsum = p0 + p1;
    #pragma unroll
    for (int mk = 1; mk <= 32; mk <<= 1) lsum += __shfl_xor(lsum, mk);
    if ((tid & 63) == 0) redM[4 + (tid >> 6)] = lsum;
    __syncthreads();
    float rcp = 1.f / (redM[4] + redM[5] + redM[6] + redM[7]);

    float4 acc = make_float4(0.f,0.f,0.f,0.f);
    for (int mm = 0; mm < 32; ++mm) {
      int m = mm*16 + m16;
      float4 hv = hpS4[m*16 + og];
      float p = pS[m];
      acc.x += hv.x*p; acc.y += hv.y*p; acc.z += hv.z*p; acc.w += hv.w*p;
    }
    acc.x += __shfl_xor(acc.x, 16); acc.y += __shfl_xor(acc.y, 16);
    acc.z += __shfl_xor(acc.z, 16); acc.w += __shfl_xor(acc.w, 16);
    acc.x += __shfl_xor(acc.x, 32); acc.y += __shfl_xor(acc.y, 32);
    acc.z += __shfl_xor(acc.z, 32); acc.w += __shfl_xor(acc.w, 32);
    __syncthreads();
    if ((tid & 63) < 16) ((float4*)redS)[(tid >> 6)*16 + (tid & 15)] = acc;
    __syncthreads();
    if (tid < 16) {
      float4 s = make_float4(0.f,0.f,0.f,0.f);
      #pragma unroll
      for (int w = 0; w < 4; ++w) {
        float4 v = ((float4*)redS)[w*16 + tid];
        s.x += v.x; s.y += v.y; s.z += v.z; s.w += v.w;
      }
      float4 bv = *(const float4*)(b2 + tid*4);
      outS[n*64 + tid*4 + 0] = elu_f(s.x*rcp + bv.x);
      outS[n*64 + tid*4 + 1] = elu_f(s.y*rcp + bv.y);
      outS[n*64 + tid*4 + 2] = elu_f(s.z*rcp + bv.z);
      outS[n*64 + tid*4 + 3] = elu_f(s.w*rcp + bv.w);
    }
    __syncthreads();
  }

  if (tid < 64) vS[tid] = outS[tid] * outS[64 + tid];
  __syncthreads();
  if (tid < 192) {
    float a = fc1_b[tid];
    for (int o = 0; o < 64; ++o) a += vS[o]*fc1_w[o*192 + tid];
    y1S[tid] = a > 0.f ? a : 0.f;
  }
  __syncthreads();
  if (tid < 64) {
    float a = fc2_b[tid];
    for (int j = 0; j < 192; ++j) a += y1S[j]*fc2_w[j*64 + tid];
    vS[tid] = a > 0.f ? a : 0.f;
  }
  __syncthreads();
  if (tid == 0) {
    float t0 = fc3_b[0], t1 = fc3_b[1];
    for (int k = 0; k < 64; ++k) {
      float y = vS[k];
      t0 += y*fc3_w[k*2 + 0];
      t1 += y*fc3_w[k*2 + 1];
    }
    float mx = fmaxf(t0, t1);
    float lse = mx + logf(__expf(t0 - mx) + __expf(t1 - mx));
    out[b*2 + 0] = t0 - lse;
    out[b*2 + 1] = t1 - lse;
  }
}

// ---------------------------------------------------------------------------
extern "C" void kernel_launch(void* const* d_in, const int* in_sizes, int n_in,
                              void* d_out, int out_size, void* d_ws, size_t ws_size,
                              hipStream_t stream) {
  const float* emb    = (const float*)d_in[0];
  const int*   adj    = (const int*)d_in[1];
  const float* vt     = (const float*)d_in[2];
  const float* w1     = (const float*)d_in[3];
  const float* a_src1 = (const float*)d_in[4];
  const float* a_dst1 = (const float*)d_in[5];
  const float* b1     = (const float*)d_in[6];
  const float* w2     = (const float*)d_in[7];
  const float* a_src2 = (const float*)d_in[8];
  const float* a_dst2 = (const float*)d_in[9];
  const float* b2     = (const float*)d_in[10];
  const float* fc1_w  = (const float*)d_in[11];
  const float* fc1_b  = (const float*)d_in[12];
  const float* fc2_w  = (const float*)d_in[13];
  const float* fc2_b  = (const float*)d_in[14];
  const float* fc3_w  = (const float*)d_in[15];
  const float* fc3_b  = (const float*)d_in[16];

  char* ws = (char*)d_ws;
  int* counts  = (int*)ws;
  int* rowlist = (int*)(ws + 4096);
  u64* maskw   = (u64*)(ws + 204800);
  u16* w1t     = (u16*)(ws + 1310720);
  u16* w2t     = (u16*)(ws + 3670016);
  u16* hp1b    = (u16*)(ws + 3932160);           // 16.78 MB
  float* hp2   = (float*)(ws + 20709376);        // 4.19 MB
  u16* w1tt    = (u16*)(ws + 20709376);          // 2.36 MB, ALIASES hp2:
                                                 // consumed by gemm1 before
                                                 // gemm2 writes hp2.
  u16* xbf     = (u16*)(ws + 24903680);          // 16.78 MB -> end 41.7 MB

  hipMemsetAsync(counts, 0, 16, stream);
  front_kernel<<<4268, 256, 0, stream>>>(adj, vt, w1, w2,
                                         maskw, rowlist, counts, w1t, w2t);
  retile_w1<<<dim3(12, 24), 256, 0, stream>>>(w1t, w1tt);

  gemm1_mfma<<<dim3(1056), 256, 0, stream>>>(emb, w1tt, rowlist, counts, hp1b);

  size_t sm1 = 72448;
  gat1_attn<<<BB*NH*2, 1024, sm1, stream>>>(hp1b, maskw, a_src1, a_dst1, b1, xbf);

  gemm2_mfma<<<dim3(768), 256, 0, stream>>>(xbf, w2t, rowlist, counts, hp2);

  size_t sm2 = (size_t)(32768 + 512 + 512 + 512 + 256 + 128 + 64 + 192 + 8) * 4;
  gat2_final<<<BB, 256, sm2, stream>>>(hp2, maskw, a_src2, a_dst2, b2,
                                       fc1_w, fc1_b, fc2_w, fc2_b, fc3_w, fc3_b,
                                       (float*)d_out);
}

// Round 20
// 138.353 us; speedup vs baseline: 1.1328x; 1.0076x over previous
//
#include <hip/hip_runtime.h>

#define BB   32
#define NN   512
#define NH   8
#define FIN  768
#define FHID 64
#define NROWS (BB*NN)   // 16384

typedef __attribute__((ext_vector_type(8))) short bf16x8;
typedef __attribute__((ext_vector_type(4))) short s16x4;
typedef __attribute__((ext_vector_type(4))) float f32x4;
typedef unsigned long long u64;
typedef unsigned short u16;
typedef long i64;

__device__ __forceinline__ float lrelu_f(float s){ return fmaxf(s, 0.2f*s); }
__device__ __forceinline__ float elu_f(float s){ return s > 0.f ? s : expm1f(s); }
__device__ __forceinline__ short f2bf(float f){
  unsigned u = __float_as_uint(f);
  return (short)((u + 0x7fffu + ((u >> 16) & 1u)) >> 16);   // RNE
}
__device__ __forceinline__ float bf2f(short s){
  return __uint_as_float(((unsigned)(u16)s) << 16);
}
// packed {bf16(lo), bf16(hi)} in one u32 — single VOP3 (RNE)
__device__ __forceinline__ unsigned cvt_pk_bf16(float lo, float hi){
  unsigned r;
  asm("v_cvt_pk_bf16_f32 %0, %1, %2" : "=v"(r) : "v"(lo), "v"(hi));
  return r;
}
// raw HW 2^x (1 instruction; very negative input -> 0)
__device__ __forceinline__ float exp2_fast(float x){
  float r;
  asm("v_exp_f32 %0, %1" : "=v"(r) : "v"(x));
  return r;
}
// packed {fp8(lo), fp8(hi)} in low 16 bits (OCP e4m3)
__device__ __forceinline__ unsigned cvt_pk_fp8(float lo, float hi){
  return (unsigned)__builtin_amdgcn_cvt_pk_fp8_f32(lo, hi, 0, false);
}
// async global->LDS DMA, 16B per lane (wave-uniform LDS base + lane*16)
__device__ __forceinline__ void gll16(const void* g, void* l){
  __builtin_amdgcn_global_load_lds(
      (const __attribute__((address_space(1))) void*)g,
      (__attribute__((address_space(3))) void*)l, 16, 0, 0);
}

// ---------------------------------------------------------------------------
// K1 (fused front): blocks [0..107] = conv_w, [108..171] = rowlist,
// [172..4267] = prep. (unchanged from round 18)
// ---------------------------------------------------------------------------
__global__ __launch_bounds__(256) void front_kernel(
    const int* __restrict__ adj, const float* __restrict__ vt,
    const float* __restrict__ w1, const float* __restrict__ w2,
    u64* __restrict__ maskw, int* __restrict__ rowlist, int* __restrict__ counts,
    u16* __restrict__ w1t, u16* __restrict__ w2t)
{
  __shared__ float tile[64][68];
  __shared__ int lc[3];
  __shared__ int lbase[3];
  int gb = blockIdx.x;
  int tid = threadIdx.x;

  if (gb < 108) {
    int bid = gb % 27, kq = gb / 27;
    const float* src; u16* dst; int K;
    if (bid < 24) { src = w1 + (long)bid*768*64; dst = w1t + (long)bid*64*768; K = 768; }
    else { int t = bid - 24; src = w2 + (long)t*512*64; dst = w2t + (long)t*64*512; K = 512; }
    int kstart = kq * (K >> 2), kend = kstart + (K >> 2);
    for (int k0 = kstart; k0 < kend; k0 += 64) {
      __syncthreads();
      #pragma unroll
      for (int i = 0; i < 4; ++i) {
        int kk = i*16 + (tid >> 4);
        int oo = (tid & 15) * 4;
        float4 v = *(const float4*)(src + (long)(k0 + kk)*64 + oo);
        *(float4*)&tile[kk][oo] = v;
      }
      __syncthreads();
      int o = tid >> 2, kp = (tid & 3) * 16;
      unsigned pk[8];
      #pragma unroll
      for (int j = 0; j < 8; ++j)
        pk[j] = cvt_pk_bf16(tile[kp + 2*j][o], tile[kp + 2*j + 1][o]);
      u16* d = dst + (long)o*K + k0 + kp;
      #pragma unroll
      for (int j = 0; j < 8; ++j) *(unsigned*)(d + 2*j) = pk[j];
    }
  } else if (gb < 172) {
    int row = (gb - 108) * 256 + tid;
    if (tid < 3) lc[tid] = 0;
    __syncthreads();
    const float* v = vt + (long)row*3;
    int t = v[1] > 0.5f ? 1 : (v[2] > 0.5f ? 2 : 0);
    int p = atomicAdd(&lc[t], 1);
    __syncthreads();
    if (tid < 3) lbase[tid] = atomicAdd(&counts[tid], lc[tid]);
    __syncthreads();
    rowlist[t*NROWS + lbase[t] + p] = row;
  } else {
    int row  = (gb - 172) * 4 + (tid >> 6);
    int lane = tid & 63;
    const int* arow = adj + (long)row * NN;
    #pragma unroll
    for (int w = 0; w < 8; ++w) {
      u64 bal = __ballot(arow[w*64 + lane] > 0);
      if (lane == 0) maskw[(long)row*8 + w] = bal;
    }
  }
}

// ---------------------------------------------------------------------------
// K2b: retile w1t into gemm1's LDS image order. (unchanged)
// ---------------------------------------------------------------------------
__global__ __launch_bounds__(256) void retile_w1(
    const u16* __restrict__ w1t, u16* __restrict__ w1tt)
{
  int thb = blockIdx.x;      // 0..11 = t*4 + hb
  int kiter = blockIdx.y;    // 0..23
  int t = thb >> 2, hb = thb & 3;
  int tid = threadIdx.x;
  u16* dst = w1tt + ((long)thb*24 + kiter)*4096;
  #pragma unroll
  for (int c = 0; c < 2; ++c) {
    int u = c*256 + tid;
    int kg = u >> 7, col = u & 127;
    int head = hb*2 + (col >> 6), o = col & 63;
    int k = kiter*32 + kg*8;
    const u16* s = w1t + (((long)t*8 + head)*64 + o)*768 + k;
    *(bf16x8*)(dst + u*8) = *(const bf16x8*)s;
  }
}

// ---------------------------------------------------------------------------
// K3: layer-1 gathered GEMM, bf16 MFMA. (round-16 version, unchanged)
// ---------------------------------------------------------------------------
__global__ __launch_bounds__(256) void gemm1_mfma(
    const float* __restrict__ emb,
    const u16* __restrict__ w1tt,
    const int* __restrict__ rowlist, const int* __restrict__ counts,
    u16* __restrict__ hp1b)
{
  int i   = blockIdx.x;           // 0..1055
  int t   = i / 352;
  int r   = i - t*352;
  int cnt = counts[t];
  int xcd = r & 7;
  int q   = r >> 3;
  int hb  = q & 3;
  int rb  = (q >> 2) * 8 + xcd;
  int r0  = rb * 64;
  if (r0 >= cnt) return;

  __shared__ short aT[2][4*66*8];
  __shared__ short bT[2][4096];
  __shared__ int rowsS[64];

  int tid = threadIdx.x;
  if (tid < 64) {
    int rr = r0 + tid;
    rowsS[tid] = (rr < cnt) ? rowlist[t*NROWS + rr] : -1;
  }
  __syncthreads();

  int ar = tid >> 2, ac = tid & 3;
  int sg = rowsS[ar]; if (sg < 0) sg = rowsS[0];
  const float* aP = emb + (long)sg*768;

  const u16* bBase = w1tt + ((long)(t*4 + hb)*24)*4096;

  int wv = tid >> 6, l = tid & 63;
  int wr = wv >> 1, wc = wv & 1;
  int l15 = l & 15, lg = l >> 4;

  int aw0 = (( (ac>>1)     )*66 + ar)*8 + (ac&1)*4;
  int aw1 = (( 2 + (ac>>1) )*66 + ar)*8 + (ac&1)*4;

  f32x4 acc[2][4];
  #pragma unroll
  for (int fr = 0; fr < 2; ++fr)
    #pragma unroll
    for (int cf = 0; cf < 4; ++cf) acc[fr][cf] = (f32x4){0.f,0.f,0.f,0.f};

  gll16(bBase + tid*8,        &bT[0][tid*8]);
  gll16(bBase + (256+tid)*8,  &bT[0][(256+tid)*8]);
  float4 rA0 = *(const float4*)(aP + ac*4);
  float4 rA1 = *(const float4*)(aP + 16 + ac*4);
  {
    unsigned lo0 = cvt_pk_bf16(rA0.x, rA0.y), hi0 = cvt_pk_bf16(rA0.z, rA0.w);
    unsigned lo1 = cvt_pk_bf16(rA1.x, rA1.y), hi1 = cvt_pk_bf16(rA1.z, rA1.w);
    *(uint2*)&aT[0][aw0] = make_uint2(lo0, hi0);
    *(uint2*)&aT[0][aw1] = make_uint2(lo1, hi1);
  }
  rA0 = *(const float4*)(aP + 32 + ac*4);
  rA1 = *(const float4*)(aP + 48 + ac*4);
  __syncthreads();

  int cur = 0;
  for (int kiter = 0; kiter < 24; ++kiter) {
    if (kiter < 23) {
      const u16* bsrc = bBase + (long)(kiter+1)*4096;
      gll16(bsrc + tid*8,       &bT[cur^1][tid*8]);
      gll16(bsrc + (256+tid)*8, &bT[cur^1][(256+tid)*8]);
    }
    bf16x8 af_[2], bf_[4];
    #pragma unroll
    for (int fr = 0; fr < 2; ++fr)
      af_[fr] = *(const bf16x8*)&aT[cur][(lg*66 + wr*32 + fr*16 + l15)*8];
    #pragma unroll
    for (int cf = 0; cf < 4; ++cf)
      bf_[cf] = *(const bf16x8*)&bT[cur][(lg*128 + wc*64 + cf*16 + l15)*8];
    #pragma unroll
    for (int fr = 0; fr < 2; ++fr)
      #pragma unroll
      for (int cf = 0; cf < 4; ++cf)
        acc[fr][cf] = __builtin_amdgcn_mfma_f32_16x16x32_bf16(af_[fr], bf_[cf], acc[fr][cf], 0, 0, 0);
    if (kiter < 23) {
      unsigned lo0 = cvt_pk_bf16(rA0.x, rA0.y), hi0 = cvt_pk_bf16(rA0.z, rA0.w);
      unsigned lo1 = cvt_pk_bf16(rA1.x, rA1.y), hi1 = cvt_pk_bf16(rA1.z, rA1.w);
      *(uint2*)&aT[cur^1][aw0] = make_uint2(lo0, hi0);
      *(uint2*)&aT[cur^1][aw1] = make_uint2(lo1, hi1);
      if (kiter < 22) {
        rA0 = *(const float4*)(aP + (kiter+2)*32 + ac*4);
        rA1 = *(const float4*)(aP + (kiter+2)*32 + 16 + ac*4);
      }
    }
    __syncthreads();
    cur ^= 1;
  }

  #pragma unroll
  for (int fr = 0; fr < 2; ++fr) {
    #pragma unroll
    for (int r4 = 0; r4 < 4; ++r4) {
      int rloc = wr*32 + fr*16 + lg*4 + r4;
      int rg = rowsS[rloc];
      if (rg < 0) continue;
      long obase = ((long)(rg >> 9) * 8) * 32768 + (long)(rg & 511) * 64;
      #pragma unroll
      for (int cf = 0; cf < 4; ++cf) {
        int c = wc*64 + cf*16 + l15;
        hp1b[obase + (long)(hb*2 + (c >> 6))*32768 + (c & 63)] = (u16)f2bf(acc[fr][cf][r4]);
      }
    }
  }
}

// ---------------------------------------------------------------------------
// K5: layer-2 gathered GEMM, bf16 MFMA. (unchanged)
// ---------------------------------------------------------------------------
__global__ __launch_bounds__(256) void gemm2_mfma(
    const u16* __restrict__ xbf,
    const u16* __restrict__ w2t,
    const int* __restrict__ rowlist, const int* __restrict__ counts,
    float* __restrict__ hp2)
{
  int i   = blockIdx.x;           // 0..767
  int t   = i >> 8;
  int cnt = counts[t];
  int r0  = (i & 255) * 64;
  if (r0 >= cnt) return;

  __shared__ short aT[4*66*8];
  __shared__ short bT[4*66*8];
  __shared__ int rowsS[64];

  int tid = threadIdx.x;
  if (tid < 64) {
    int rr = r0 + tid;
    rowsS[tid] = (rr < cnt) ? rowlist[t*NROWS + rr] : -1;
  }
  __syncthreads();

  int ar = tid >> 2, ac = tid & 3;
  int sg = rowsS[ar]; if (sg < 0) sg = rowsS[0];
  long apart = ((long)(sg >> 9) * 8) * 32768 + (long)(sg & 511) * 64;

  int colb = tid >> 2, off = tid & 3;
  const u16* bP = w2t + ((long)t*64 + colb)*512;

  int wv = tid >> 6, l = tid & 63;
  int l15 = l & 15, lg = l >> 4;

  f32x4 acc[4];
  #pragma unroll
  for (int cf = 0; cf < 4; ++cf) acc[cf] = (f32x4){0.f,0.f,0.f,0.f};

  int ka0 = ac*8;
  bf16x8 ra = *(const bf16x8*)(xbf + apart + (long)(ka0 >> 6)*32768 + (ka0 & 63));
  bf16x8 rb = *(const bf16x8*)(bP + off*8);

  for (int k0 = 0; k0 < 512; k0 += 32) {
    __syncthreads();
    *(bf16x8*)&aT[(ac*66 + ar)*8]   = ra;
    *(bf16x8*)&bT[(off*66 + colb)*8] = rb;
    __syncthreads();
    if (k0 + 32 < 512) {
      int kn = k0 + 32 + ac*8;
      ra = *(const bf16x8*)(xbf + apart + (long)(kn >> 6)*32768 + (kn & 63));
      rb = *(const bf16x8*)(bP + k0 + 32 + off*8);
    }
    bf16x8 af, bfr[4];
    af = *(const bf16x8*)&aT[(lg*66 + wv*16 + l15)*8];
    #pragma unroll
    for (int cf = 0; cf < 4; ++cf)
      bfr[cf] = *(const bf16x8*)&bT[(lg*66 + cf*16 + l15)*8];
    #pragma unroll
    for (int cf = 0; cf < 4; ++cf)
      acc[cf] = __builtin_amdgcn_mfma_f32_16x16x32_bf16(af, bfr[cf], acc[cf], 0, 0, 0);
  }

  #pragma unroll
  for (int r4 = 0; r4 < 4; ++r4) {
    int rloc = wv*16 + lg*4 + r4;
    int rg = rowsS[rloc];
    if (rg < 0) continue;
    #pragma unroll
    for (int cf = 0; cf < 4; ++cf)
      hp2[(long)rg*64 + cf*16 + l15] = acc[cf][r4];
  }
}

// ---------------------------------------------------------------------------
// K4: GAT layer-1 attention. 512 blocks (2 per (b,h)), fp8 P/V LDS.
// Round-20: FACTORED EXP kept — exp2(lrelu(si+dj)) = max(Es_i*Ed_j,
// Fs_i*Fd_j), 2 transcendentals/row + 16 hoisted regs/lane; per-element
// cost is 2 muls + 1 max + select. NORMALIZER REVERTED to the trusted
// round-18 shuffle-reduce lsum + rcpS (round-19's MFMA-ones row-sum
// produced unbounded output => denominator path was broken; with a
// consistent f32 lsum the output is bounded by max|V| for any p>=0).
// ---------------------------------------------------------------------------
__global__ __launch_bounds__(1024) void gat1_attn(
    const u16* __restrict__ hp1b, const u64* __restrict__ maskw,
    const float* __restrict__ a_src, const float* __restrict__ a_dst,
    const float* __restrict__ b1, u16* __restrict__ xbf)
{
  extern __shared__ char smc[];
  char*  hpTf = smc;                          // [64 koct][66 o][8 kin] fp8  33,792
  char*  pSf  = smc + 33792;                  // [64 koct][66 row][8 kin] fp8 33,792
  float* srcS = (float*)(smc + 67584);        // [512]
  float* dstS = (float*)(smc + 69632);        // [512]
  float* asS  = (float*)(smc + 71680);        // [64]
  float* adS  = (float*)(smc + 71936);        // [64]
  float* rcpS = (float*)(smc + 72192);        // [64]   end 72,448

  const float LOG2E = 1.4426950408889634f;

  int bid = blockIdx.x;
  int bh = bid >> 1, qh = bid & 1;
  int b = bh >> 3, h = bh & 7;
  int tid = threadIdx.x;

  if (tid < 64) asS[tid] = a_src[h*64 + tid];
  else if (tid < 128) adS[tid - 64] = a_dst[h*64 + (tid - 64)];
  __syncthreads();

  // phase 0: load V slice, dots (pre-scaled by log2e), scatter V fp8
  {
    int m = tid >> 1, half = tid & 1;
    int koct = m >> 3, kin = m & 7;
    const u16* hpRow = hp1b + ((long)bh*NN + m)*64 + half*32;
    float ps = 0.f, pd = 0.f;
    #pragma unroll
    for (int qq = 0; qq < 4; ++qq) {
      bf16x8 hv = *(const bf16x8*)(hpRow + qq*8);
      int o0 = half*32 + qq*8;
      #pragma unroll
      for (int j = 0; j < 8; ++j) {
        float f = bf2f(hv[j]);
        ps += f * asS[o0 + j];
        pd += f * adS[o0 + j];
        hpTf[(koct*66 + o0 + j)*8 + kin] = (char)(cvt_pk_fp8(f, f) & 0xffu);
      }
    }
    ps += __shfl_xor(ps, 1);
    pd += __shfl_xor(pd, 1);
    if ((tid & 1) == 0) { srcS[m] = ps * LOG2E; dstS[m] = pd * LOG2E; }
  }
  __syncthreads();

  int wv = tid >> 6, lane = tid & 63;
  int l15 = lane & 15, lg = lane >> 4;
  int cgl = wv >> 2, nt = wv & 3;
  int o_out = nt*16 + l15;
  float bb  = b1[o_out];

  // hoisted per lane: Ed/Fd for k = 2*lane, 2*lane+1 in each jj-slab
  float2 Ed[4], Fd[4];
  #pragma unroll
  for (int jj = 0; jj < 4; ++jj) {
    float2 d = *(const float2*)&dstS[jj*128 + 2*lane];
    Ed[jj].x = exp2_fast(d.x);        Ed[jj].y = exp2_fast(d.y);
    Fd[jj].x = exp2_fast(0.2f*d.x);   Fd[jj].y = exp2_fast(0.2f*d.y);
  }
  int wsel = lane >> 5;
  unsigned sh = (unsigned)((2*lane) & 63);
  int pbase = ((lane >> 2)*66)*8 + 2*(lane & 3);

  for (int s = 0; s < 4; ++s) {
    int sup = qh*4 + s;
    // softmax (factored exp, unnormalized): wave wv owns rows sup*64+wv*4+{0..3}
    #pragma unroll
    for (int rr = 0; rr < 4; ++rr) {
      int rloc = wv*4 + rr;
      int row  = sup*64 + rloc;
      float srcv = srcS[row];
      float Es = exp2_fast(srcv);
      float Fs = exp2_fast(0.2f*srcv);
      const u64* mrow = maskw + ((long)(b*NN + row))*8;
      float lsum = 0.f;
      #pragma unroll
      for (int jj = 0; jj < 4; ++jj) {
        u64 w = mrow[jj*2 + wsel];
        unsigned bits = (unsigned)(w >> sh) & 3u;
        float p0 = fmaxf(Es*Ed[jj].x, Fs*Fd[jj].x);
        float p1 = fmaxf(Es*Ed[jj].y, Fs*Fd[jj].y);
        p0 = (bits & 1u) ? p0 : 0.f;
        p1 = (bits & 2u) ? p1 : 0.f;
        lsum += p0 + p1;
        *(u16*)&pSf[(jj*16*66)*8 + pbase + rloc*8] = (u16)cvt_pk_fp8(p0, p1);
      }
      #pragma unroll
      for (int mk = 1; mk <= 32; mk <<= 1) lsum += __shfl_xor(lsum, mk);
      if (lane == 0) rcpS[rloc] = 1.f / lsum;
    }
    __syncthreads();

    // PV via fp8 MFMA: wave (cgl,nt) -> rows cgl*16.., cols nt*16.., K=512
    f32x4 acc = {0.f, 0.f, 0.f, 0.f};
    #pragma unroll
    for (int ks = 0; ks < 16; ++ks) {
      int koct = ks*4 + lg;
      i64 af = *(const i64*)&pSf [(koct*66 + cgl*16 + l15)*8];
      i64 bf = *(const i64*)&hpTf[(koct*66 + nt*16  + l15)*8];
      acc = __builtin_amdgcn_mfma_f32_16x16x32_fp8_fp8(af, bf, acc, 0, 0, 0);
    }
    #pragma unroll
    for (int reg = 0; reg < 4; ++reg) {
      int rloc = cgl*16 + lg*4 + reg;
      int row  = sup*64 + rloc;
      float v = elu_f(acc[reg] * rcpS[rloc] + bb);
      xbf[((long)bh*NN + row)*64 + o_out] = (u16)f2bf(v);
    }
    __syncthreads();
  }
}

// ---------------------------------------------------------------------------
// K6: GAT layer-2 attention (rows 0,1 only) + ELU + MLP + log_softmax.
// ---------------------------------------------------------------------------
__global__ __launch_bounds__(256) void gat2_final(
    const float* __restrict__ hp2, const u64* __restrict__ maskw,
    const float* __restrict__ a_src2, const float* __restrict__ a_dst2,
    const float* __restrict__ b2,
    const float* __restrict__ fc1_w, const float* __restrict__ fc1_b,
    const float* __restrict__ fc2_w, const float* __restrict__ fc2_b,
    const float* __restrict__ fc3_w, const float* __restrict__ fc3_b,
    float* __restrict__ out)
{
  extern __shared__ float sm[];
  float* hpS  = sm;              // 32768
  float* dstS = hpS + 32768;     // 512
  float* srcS = dstS + 512;      // 512
  float* pS   = srcS + 512;      // 512
  float* redS = pS + 512;        // 256
  float* outS = redS + 256;      // 128
  float* vS   = outS + 128;      // 64
  float* y1S  = vS + 64;         // 192
  float* redM = y1S + 192;       // 8
  float4* hpS4 = (float4*)hpS;

  int b = blockIdx.x;
  int tid = threadIdx.x;
  int og = tid & 15, m16 = tid >> 4;

  for (int it = 0; it < 32; ++it) {
    int fi = it*256 + tid;
    int m = fi >> 4, o4 = fi & 15;
    hpS4[m*16 + o4] = *(const float4*)(hp2 + (long)(b*NN + m)*64 + o4*4);
  }
  __syncthreads();

  float4 as4 = *(const float4*)(a_src2 + og*4);
  float4 ad4 = *(const float4*)(a_dst2 + og*4);
  for (int it = 0; it < 32; ++it) {
    int m = it*16 + m16;
    float4 hv = hpS4[m*16 + og];
    float ls = hv.x*as4.x + hv.y*as4.y + hv.z*as4.z + hv.w*as4.w;
    float ld = hv.x*ad4.x + hv.y*ad4.y + hv.z*ad4.z + hv.w*ad4.w;
    #pragma unroll
    for (int mk = 1; mk <= 8; mk <<= 1) {
      ls += __shfl_xor(ls, mk);
      ld += __shfl_xor(ld, mk);
    }
    if (og == 0) { srcS[m] = ls; dstS[m] = ld; }
  }
  __syncthreads();

  for (int n = 0; n < 2; ++n) {
    float srcv = srcS[n];
    const u64* mrow = maskw + (long)(b*NN + n)*8;
    int m0 = tid, m1 = tid + 256;
    u64 w0 = mrow[m0 >> 6], w1 = mrow[m1 >> 6];
    float s0 = srcv + dstS[m0], s1 = srcv + dstS[m1];
    float e0 = ((w0 >> (m0 & 63)) & 1ull) ? lrelu_f(s0) : -1.0e9f;
    float e1 = ((w1 >> (m1 & 63)) & 1ull) ? lrelu_f(s1) : -1.0e9f;
    float emax = fmaxf(e0, e1);
    #pragma unroll
    for (int mk = 1; mk <= 32; mk <<= 1) emax = fmaxf(emax, __shfl_xor(emax, mk));
    if ((tid & 63) == 0) redM[tid >> 6] = emax;
    __syncthreads();
    emax = fmaxf(fmaxf(redM[0], redM[1]), fmaxf(redM[2], redM[3]));
    float p0 = __expf(e0 - emax), p1 = __expf(e1 - emax);
    pS[m0] = p0; pS[m1] = p1;
    float lsum = p0 + p1;
    #pragma unroll
    for (int mk = 1; mk <= 32; mk <<= 1) lsum += __shfl_xor(lsum, mk);
    if ((tid & 63) == 0) redM[4 + (tid >> 6)] = lsum;
    __syncthreads();
    float rcp = 1.f / (redM[4] + redM[5] + redM[6] + redM[7]);

    float4 acc = make_float4(0.f,0.f,0.f,0.f);
    for (int mm = 0; mm < 32; ++mm) {
      int m = mm*16 + m16;
      float4 hv = hpS4[m*16 + og];
      float p = pS[m];
      acc.x += hv.x*p; acc.y += hv.y*p; acc.z += hv.z*p; acc.w += hv.w*p;
    }
    acc.x += __shfl_xor(acc.x, 16); acc.y += __shfl_xor(acc.y, 16);
    acc.z += __shfl_xor(acc.z, 16); acc.w += __shfl_xor(acc.w, 16);
    acc.x += __shfl_xor(acc.x, 32); acc.y += __shfl_xor(acc.y, 32);
    acc.z += __shfl_xor(acc.z, 32); acc.w += __shfl_xor(acc.w, 32);
    __syncthreads();
    if ((tid & 63) < 16) ((float4*)redS)[(tid >> 6)*16 + (tid & 15)] = acc;
    __syncthreads();
    if (tid < 16) {
      float4 s = make_float4(0.f,0.f,0.f,0.f);
      #pragma unroll
      for (int w = 0; w < 4; ++w) {
        float4 v = ((float4*)redS)[w*16 + tid];
        s.x += v.x; s.y += v.y; s.z += v.z; s.w += v.w;
      }
      float4 bv = *(const float4*)(b2 + tid*4);
      outS[n*64 + tid*4 + 0] = elu_f(s.x*rcp + bv.x);
      outS[n*64 + tid*4 + 1] = elu_f(s.y*rcp + bv.y);
      outS[n*64 + tid*4 + 2] = elu_f(s.z*rcp + bv.z);
      outS[n*64 + tid*4 + 3] = elu_f(s.w*rcp + bv.w);
    }
    __syncthreads();
  }

  if (tid < 64) vS[tid] = outS[tid] * outS[64 + tid];
  __syncthreads();
  if (tid < 192) {
    float a = fc1_b[tid];
    for (int o = 0; o < 64; ++o) a += vS[o]*fc1_w[o*192 + tid];
    y1S[tid] = a > 0.f ? a : 0.f;
  }
  __syncthreads();
  if (tid < 64) {
    float a = fc2_b[tid];
    for (int j = 0; j < 192; ++j) a += y1S[j]*fc2_w[j*64 + tid];
    vS[tid] = a > 0.f ? a : 0.f;
  }
  __syncthreads();
  if (tid == 0) {
    float t0 = fc3_b[0], t1 = fc3_b[1];
    for (int k = 0; k < 64; ++k) {
      float y = vS[k];
      t0 += y*fc3_w[k*2 + 0];
      t1 += y*fc3_w[k*2 + 1];
    }
    float mx = fmaxf(t0, t1);
    float lse = mx + logf(__expf(t0 - mx) + __expf(t1 - mx));
    out[b*2 + 0] = t0 - lse;
    out[b*2 + 1] = t1 - lse;
  }
}

// ---------------------------------------------------------------------------
extern "C" void kernel_launch(void* const* d_in, const int* in_sizes, int n_in,
                              void* d_out, int out_size, void* d_ws, size_t ws_size,
                              hipStream_t stream) {
  const float* emb    = (const float*)d_in[0];
  const int*   adj    = (const int*)d_in[1];
  const float* vt     = (const float*)d_in[2];
  const float* w1     = (const float*)d_in[3];
  const float* a_src1 = (const float*)d_in[4];
  const float* a_dst1 = (const float*)d_in[5];
  const float* b1     = (const float*)d_in[6];
  const float* w2     = (const float*)d_in[7];
  const float* a_src2 = (const float*)d_in[8];
  const float* a_dst2 = (const float*)d_in[9];
  const float* b2     = (const float*)d_in[10];
  const float* fc1_w  = (const float*)d_in[11];
  const float* fc1_b  = (const float*)d_in[12];
  const float* fc2_w  = (const float*)d_in[13];
  const float* fc2_b  = (const float*)d_in[14];
  const float* fc3_w  = (const float*)d_in[15];
  const float* fc3_b  = (const float*)d_in[16];

  char* ws = (char*)d_ws;
  int* counts  = (int*)ws;
  int* rowlist = (int*)(ws + 4096);
  u64* maskw   = (u64*)(ws + 204800);
  u16* w1t     = (u16*)(ws + 1310720);
  u16* w2t     = (u16*)(ws + 3670016);
  u16* hp1b    = (u16*)(ws + 3932160);           // 16.78 MB
  float* hp2   = (float*)(ws + 20709376);        // 4.19 MB
  u16* w1tt    = (u16*)(ws + 20709376);          // 2.36 MB, ALIASES hp2:
                                                 // consumed by gemm1 before
                                                 // gemm2 writes hp2.
  u16* xbf     = (u16*)(ws + 24903680);          // 16.78 MB -> end 41.7 MB

  hipMemsetAsync(counts, 0, 16, stream);
  front_kernel<<<4268, 256, 0, stream>>>(adj, vt, w1, w2,
                                         maskw, rowlist, counts, w1t, w2t);
  retile_w1<<<dim3(12, 24), 256, 0, stream>>>(w1t, w1tt);

  gemm1_mfma<<<dim3(1056), 256, 0, stream>>>(emb, w1tt, rowlist, counts, hp1b);

  size_t sm1 = 72448;
  gat1_attn<<<BB*NH*2, 1024, sm1, stream>>>(hp1b, maskw, a_src1, a_dst1, b1, xbf);

  gemm2_mfma<<<dim3(768), 256, 0, stream>>>(xbf, w2t, rowlist, counts, hp2);

  size_t sm2 = (size_t)(32768 + 512 + 512 + 512 + 256 + 128 + 64 + 192 + 8) * 4;
  gat2_final<<<BB, 256, sm2, stream>>>(hp2, maskw, a_src2, a_dst2, b2,
                                       fc1_w, fc1_b, fc2_w, fc2_b, fc3_w, fc3_b,
                                       (float*)d_out);
}